// Round 10
// baseline (170.574 us; speedup 1.0000x reference)
//
#include <hip/hip_runtime.h>
#include <math.h>

// Problem constants (fixed by setup_inputs)
constexpr int N_ = 8, C_ = 256, F_ = 16, WH_ = 784;
constexpr int CH_STRIDE = F_ * WH_;        // 12544 floats between channels
constexpr int COUT_SZ = N_ * F_ * WH_;     // 100352 floats (c output)
constexpr int QP = 392;                    // positions per block (half row)
constexpr int PASS_P = 64;                 // positions per pass (one per lane)
constexpr int NPASS = 7;                   // 6 full + tail (8 valid lanes)
constexpr int TAILV = QP - (NPASS - 1) * PASS_P;  // 8
constexpr int CPS = 16;                    // channels per wave (16 waves x 16)
constexpr int PSTR = 17;                   // padded part stride (gcd(17,32)=1)
constexpr int SOFF = 256 * C_;             // ws offset of S partials

__device__ inline float wave_reduce_sum(float v) {
#pragma unroll
  for (int o = 32; o > 0; o >>= 1) v += __shfl_down(v, o, 64);
  return v;
}

// ---------------- Kernel 1: fused single-read, register-resident l ---------
// R7-R9 post-mortem: EVERY LDS-tile staging variant (sync / gload_lds /
// reg-staged; TILE 28/56; 1 or 2 blocks/CU) pins at ~5-6 B/cyc/CU. The only
// structure measured at 14.6 B/cyc/CU on this stride (R0 pass A) used
// per-lane SCALAR loads (wave = 64 contiguous positions = ONE 256-B segment
// per wave-instr) feeding registers. This kernel ports that shape into the
// single-read fused algorithm:
//   wave wv = 16-channel slice; lanes = 64 contiguous positions.
//   Per pass: 16 scalar loads -> lv[16] regs; partial dot -> part[64][17]
//   (LDS, double-buffered); ONE barrier; every wave redundantly sums the 16
//   partials for its lane (c complete), exp -> e; G-accum e*lv[k] from the
//   SAME registers (the l-reuse lives in VGPRs, no LDS tile at all).
//   Pass t+1's loads are issued into the ping-pong bank before pass t's dot
//   -> >=16 wave-loads in flight across the barrier.
// Pass loop fully unrolled so lv[t&1] is compile-time (rule #20, R5 lesson).
// Max-free online softmax (proven R2-R9): g_out = G/S combined by K2.
__global__ __launch_bounds__(1024, 4) void fused_kernel(
    const float* __restrict__ l, const float* __restrict__ g,
    const float* __restrict__ w, float* __restrict__ out,
    float* __restrict__ ws) {
  __shared__ float part[2][PASS_P][PSTR];  // 8704 B, double-buffered
  __shared__ float w_s[C_];
  __shared__ float red_s[16];
  __shared__ float gb_s;

  const int bid = blockIdx.x;
  const int nf = bid >> 1, half = bid & 1;
  const int n = nf >> 4, f = nf & 15;
  const int tid = threadIdx.x;
  const int lane = tid & 63, wv = tid >> 6;

  const size_t gbase =
      (size_t)n * (C_ * CH_STRIDE) + (size_t)f * WH_ + half * QP;
  // this thread's l base: channel slice wv*16, position = lane
  const float* lb = l + gbase + (size_t)(wv * CPS) * CH_STRIDE + lane;

  float lv[2][CPS];
  // issue pass-0 loads immediately; they fly under the whole prologue
#pragma unroll
  for (int k = 0; k < CPS; ++k) lv[0][k] = lb[(size_t)k * CH_STRIDE];

  // ---- prologue: w into LDS, gb = sum_c g[n,c]*w[c] ----
  if (tid < C_) w_s[tid] = w[tid];
  float gv = (tid < C_) ? g[n * C_ + tid] * w[tid] : 0.f;
  gv = wave_reduce_sum(gv);
  if (lane == 0) red_s[wv] = gv;
  __syncthreads();  // also makes w_s visible
  if (tid == 0) {
    float s = 0.f;
#pragma unroll
    for (int i = 0; i < 16; ++i) s += red_s[i];
    gb_s = s;
  }
  __syncthreads();
  const float gb = gb_s;

  // hoist this wave's 16 w coefficients into registers (read once)
  float wc[CPS];
#pragma unroll
  for (int k = 0; k < CPS; ++k) wc[k] = w_s[wv * CPS + k];

  float gacc[CPS];
#pragma unroll
  for (int k = 0; k < CPS; ++k) gacc[k] = 0.f;
  float s_part = 0.f;  // S partial (wave 0 only)

#pragma unroll
  for (int t = 0; t < NPASS; ++t) {
    const int cb = t & 1, nb = cb ^ 1;  // compile-time after full unroll

    // issue pass t+1 loads into the other register bank (in flight across
    // the dot, the barrier, and the G-accum of this pass)
    if (t + 1 < NPASS) {
      const float* lp = lb + (t + 1) * PASS_P;
      if (t + 1 == NPASS - 1) {
        // tail pass: only lanes < TAILV are in-bounds; exec-mask the loads
        if (lane < TAILV) {
#pragma unroll
          for (int k = 0; k < CPS; ++k) lv[nb][k] = lp[(size_t)k * CH_STRIDE];
        } else {
#pragma unroll
          for (int k = 0; k < CPS; ++k) lv[nb][k] = 0.f;
        }
      } else {
#pragma unroll
        for (int k = 0; k < CPS; ++k) lv[nb][k] = lp[(size_t)k * CH_STRIDE];
      }
    }

    // ---- partial dot for this wave's 16 channels (waits on lv[cb]) ----
    float pc = 0.f;
#pragma unroll
    for (int k = 0; k < CPS; ++k) pc = fmaf(lv[cb][k], wc[k], pc);
    part[cb][lane][wv] = pc;  // stride 17 across lanes: conflict-free
    __syncthreads();          // part[cb] complete (part[nb] untouched)

    // ---- complete c for this lane's position (redundant per wave) ----
    float rs = 0.f;
#pragma unroll
    for (int j = 0; j < 16; ++j) rs += part[cb][lane][j];
    const bool act = (t < NPASS - 1) || (lane < TAILV);
    const float cp = rs + gb;
    float e = 0.f;
    if (act) {
      e = __expf(cp);
      if (wv == 0) out[nf * WH_ + half * QP + t * PASS_P + lane] = cp;
    }
    if (wv == 0) s_part += e;

    // ---- G-accum from the SAME registers: gacc[k] += e * l[c,p] ----
#pragma unroll
    for (int k = 0; k < CPS; ++k) gacc[k] = fmaf(e, lv[cb][k], gacc[k]);
    // no second barrier: next pass writes part[nb]; part[cb] is rewritten
    // only in pass t+2, after pass t+1's barrier -> all reads here are safe
  }

  // ---- epilogue: publish partials ----
#pragma unroll
  for (int k = 0; k < CPS; ++k) {
    const float r = wave_reduce_sum(gacc[k]);
    if (lane == 0) ws[bid * C_ + wv * CPS + k] = r;  // G partial
  }
  if (wv == 0) {
    const float sp = wave_reduce_sum(s_part);
    if (lane == 0) ws[SOFF + bid] = sp;  // S partial
  }
}

// ---------------- Kernel 2: combine half partials -> g_out ----------------
// 32768 outputs = 32 blocks x 1024 threads; one (nf, c) each.
__global__ __launch_bounds__(1024) void combine_kernel(
    float* __restrict__ out, const float* __restrict__ ws) {
  const int tg = blockIdx.x * 1024 + threadIdx.x;
  const int nf = tg >> 8, c = tg & 255;
  const int n = nf >> 4, f = nf & 15;
  const int b0 = nf << 1;
  const float G = ws[(b0 + 0) * C_ + c] + ws[(b0 + 1) * C_ + c];
  const float S = ws[SOFF + b0] + ws[SOFF + b0 + 1];
  out[COUT_SZ + (size_t)(n * C_ + c) * F_ + f] = G / S;
}

extern "C" void kernel_launch(void* const* d_in, const int* in_sizes, int n_in,
                              void* d_out, int out_size, void* d_ws,
                              size_t ws_size, hipStream_t stream) {
  const float* l = (const float*)d_in[0];
  const float* g = (const float*)d_in[1];
  const float* w = (const float*)d_in[2];
  float* out = (float*)d_out;
  float* ws = (float*)d_ws;  // [0,65536): G partials; [65536,65792): S
  fused_kernel<<<dim3(2 * N_ * F_), dim3(1024), 0, stream>>>(l, g, w, out, ws);
  combine_kernel<<<dim3(32), dim3(1024), 0, stream>>>(out, ws);
}

// Round 11
// 158.515 us; speedup vs baseline: 1.0761x; 1.0761x over previous
//
#include <hip/hip_runtime.h>
#include <math.h>

// Problem constants (fixed by setup_inputs)
constexpr int N_ = 8, C_ = 256, F_ = 16, WH_ = 784;
constexpr int CH_STRIDE = F_ * WH_;        // 12544 floats between channels
constexpr int COUT_SZ = N_ * F_ * WH_;     // 100352 floats (c output)
constexpr int QP = 392;                    // positions per block (half row)
constexpr int TILE = 28;                   // positions per tile
constexpr int NT = 14;                     // tiles per block (14*28 = 392)
constexpr int F4PT = TILE / 4;             // 7 float4 per channel per tile
constexpr int TILE_F = C_ * TILE;          // 7168 floats per buffer (28 KB)
constexpr int SOFF = 256 * C_;             // ws offset of S partials

__device__ inline float wave_reduce_sum(float v) {
#pragma unroll
  for (int o = 32; o > 0; o >>= 1) v += __shfl_down(v, o, 64);
  return v;
}

// Async global->LDS, 16B/lane. LDS dest wave-uniform base + lane*16 (m104).
__device__ inline void gload16(const float* gp, float* lp) {
  __builtin_amdgcn_global_load_lds(
      (const __attribute__((address_space(1))) void*)gp,
      (__attribute__((address_space(3))) void*)lp, 16, 0, 0);
}

// ---------------- Kernel 1: fused single-read, counted-vmcnt pipeline ------
// R6-R10 post-mortem: every variant drained vmcnt to 0 at each tile barrier
// (__syncthreads semantics) -> the issue of tile t+2 waits for the LAST line
// of t+1 -> memory hole every tile -> delivery pinned at 5-6 B/cyc/CU.
// This round applies T4 (counted vmcnt, never 0 in the loop; m218 +38-73%):
// 3 buffers, waves 0..13 issue EXACTLY 2 gload_lds per tile (uniform ->
// static count sound), per tile: issue t+2; vmcnt(4) [waits tile t only;
// t+1/t+2 stay in flight]; raw s_barrier; c-phase; lgkm barrier; G-phase;
// raw s_barrier. NO other vmem ops in the loop (c output goes to LDS
// c_save, flushed in the epilogue -- stores would corrupt the vmcnt count).
// LDS [c][28] b32 reads are exactly 2-way bank conflicts (free, m136) in
// both phases: bank = (28*c + p) % 32, c and c+8 alias, all else distinct.
// Max-free online softmax (proven R2-R10): S += sum exp(c), G_c += sum e*l;
// g_out = G/S combined across the two halves by K2.
#define TILE_BODY(T, CUR, VMWAIT)                                            \
  do {                                                                       \
    if ((T) + 2 < NT && stg) {                                               \
      const float* lp_ = l + gbase + ((T) + 2) * TILE;                       \
      gload16(lp_ + ogA, nx2 + ldsA);                                        \
      gload16(lp_ + ogB, nx2 + ldsB);                                        \
    }                                                                        \
    asm volatile(VMWAIT ::: "memory");                                       \
    __builtin_amdgcn_s_barrier();                                            \
    __builtin_amdgcn_sched_barrier(0);                                       \
    if (tid < TILE * 16) { /* c-phase: 28 pos x 16 slices (waves 0..6) */    \
      float acc = 0.f;                                                       \
      _Pragma("unroll") for (int k = 0; k < 16; ++k) {                       \
        const int c_ = s16 + (k << 4);                                       \
        acc = fmaf((CUR)[c_ * TILE + p16], w_s[c_], acc);                    \
      }                                                                      \
      acc += __shfl_down(acc, 8, 64);                                        \
      acc += __shfl_down(acc, 4, 64);                                        \
      acc += __shfl_down(acc, 2, 64);                                        \
      acc += __shfl_down(acc, 1, 64);                                        \
      if (s16 == 0) {                                                        \
        const float cp = acc + gb;                                           \
        c_save[(T) * TILE + p16] = cp;                                       \
        const float e_ = __expf(cp);                                         \
        e_s[p16] = e_;                                                       \
        s_part += e_;                                                        \
      }                                                                      \
    }                                                                        \
    asm volatile("s_waitcnt lgkmcnt(0)" ::: "memory");                       \
    __builtin_amdgcn_s_barrier();                                            \
    __builtin_amdgcn_sched_barrier(0);                                       \
    { /* G-phase: all 16 waves, channel gc, positions pbq..pbq+6 */          \
      _Pragma("unroll") for (int j = 0; j < F4PT; ++j)                       \
        gacc = fmaf((CUR)[gc * TILE + pbq + j], e_s[pbq + j], gacc);         \
    }                                                                        \
    asm volatile("s_waitcnt lgkmcnt(0)" ::: "memory");                       \
    __builtin_amdgcn_s_barrier();                                            \
  } while (0)

__global__ __launch_bounds__(1024, 4) void fused_kernel(
    const float* __restrict__ l, const float* __restrict__ g,
    const float* __restrict__ w, float* __restrict__ out,
    float* __restrict__ ws) {
  extern __shared__ float dbuf[];  // 3 * TILE_F floats (86016 B)
  __shared__ float w_s[C_];
  __shared__ float e_s[TILE];
  __shared__ float c_save[QP];
  __shared__ float red_s[16];
  __shared__ float gb_s;

  const int bid = blockIdx.x;
  const int nf = bid >> 1, half = bid & 1;
  const int n = nf >> 4, f = nf & 15;
  const int tid = threadIdx.x;
  const int lane = tid & 63, wv = tid >> 6;

  const size_t gbase =
      (size_t)n * (C_ * CH_STRIDE) + (size_t)f * WH_ + half * QP;

  // ---- stage mapping: 1792 float4/tile; waves 0..13 issue exactly 2 ----
  const bool stg = (tid < 896);
  const int cA = tid / F4PT, jA = tid - cA * F4PT;
  const int ogA = cA * CH_STRIDE + (jA << 2);
  const int sB = 896 + tid;
  const int cB = sB / F4PT, jB = sB - cB * F4PT;
  const int ogB = cB * CH_STRIDE + (jB << 2);
  const int ldsA = wv << 8;           // uniform float offset: slot = tid
  const int ldsB = 3584 + (wv << 8);  // slot = 896 + tid

  float* b0 = dbuf;
  float* b1 = dbuf + TILE_F;
  float* b2 = dbuf + 2 * TILE_F;

  // w,g loads FIRST (oldest in vmcnt FIFO), then the DMA issues: the
  // compiler's wait for w/g retires only the oldest 2, keeping DMA in flight
  const float wreg = (tid < C_) ? w[tid] : 0.f;
  const float greg = (tid < C_) ? g[n * C_ + tid] : 0.f;
  if (stg) {
    const float* lp0 = l + gbase;
    gload16(lp0 + ogA, b0 + ldsA);
    gload16(lp0 + ogB, b0 + ldsB);
    const float* lp1 = l + gbase + TILE;
    gload16(lp1 + ogA, b1 + ldsA);
    gload16(lp1 + ogB, b1 + ldsB);
  }

  // ---- prologue: w into LDS, gb = sum_c g[n,c]*w[c] (raw barriers only) --
  if (tid < C_) w_s[tid] = wreg;
  float gv = wreg * greg;
  gv = wave_reduce_sum(gv);
  if (lane == 0) red_s[wv] = gv;
  asm volatile("s_waitcnt lgkmcnt(0)" ::: "memory");
  __builtin_amdgcn_s_barrier();
  if (tid == 0) {
    float s = 0.f;
#pragma unroll
    for (int i = 0; i < 16; ++i) s += red_s[i];
    gb_s = s;
  }
  asm volatile("s_waitcnt lgkmcnt(0)" ::: "memory");
  __builtin_amdgcn_s_barrier();
  const float gb = gb_s;

  // phase mappings
  const int p16 = tid >> 4, s16 = tid & 15;  // c-phase
  const int gc = tid >> 2, q = tid & 3;      // G-phase
  const int pbq = q * F4PT;

  float gacc = 0.f;    // G partial: channel gc, positions pbq..pbq+6, all t
  float s_part = 0.f;  // S partial (s16==0 threads of waves 0..6)

  float* cur = b0;
  float* nx1 = b1;
  float* nx2 = b2;

#pragma unroll 1
  for (int t = 0; t < NT - 2; ++t) {  // t = 0..11: steady state, vmcnt(4)
    TILE_BODY(t, cur, "s_waitcnt vmcnt(4)");
    float* tmp = cur; cur = nx1; nx1 = nx2; nx2 = tmp;
  }
  TILE_BODY(NT - 2, cur, "s_waitcnt vmcnt(2)");
  { float* tmp = cur; cur = nx1; nx1 = nx2; nx2 = tmp; }
  TILE_BODY(NT - 1, cur, "s_waitcnt vmcnt(0)");

  // ---- epilogue: publish partials + flush c ----
  gacc += __shfl_down(gacc, 2, 64);
  gacc += __shfl_down(gacc, 1, 64);
  if (q == 0) ws[bid * C_ + gc] = gacc;  // 256 G partials per block

  float sp = wave_reduce_sum(s_part);
  if (lane == 0) red_s[wv] = sp;
  __syncthreads();  // safe now: DMA drained; also makes c_save visible
  if (tid == 0) {
    float ssum = 0.f;
#pragma unroll
    for (int i = 0; i < 16; ++i) ssum += red_s[i];
    ws[SOFF + bid] = ssum;  // S partial
  }
  if (tid < QP) out[nf * WH_ + half * QP + tid] = c_save[tid];  // coalesced
}

// ---------------- Kernel 2: combine half partials -> g_out ----------------
// 32768 outputs = 32 blocks x 1024 threads; one (nf, c) each.
__global__ __launch_bounds__(1024) void combine_kernel(
    float* __restrict__ out, const float* __restrict__ ws) {
  const int tg = blockIdx.x * 1024 + threadIdx.x;
  const int nf = tg >> 8, c = tg & 255;
  const int n = nf >> 4, f = nf & 15;
  const int b0 = nf << 1;
  const float G = ws[(b0 + 0) * C_ + c] + ws[(b0 + 1) * C_ + c];
  const float S = ws[SOFF + b0] + ws[SOFF + b0 + 1];
  out[COUT_SZ + (size_t)(n * C_ + c) * F_ + f] = G / S;
}

extern "C" void kernel_launch(void* const* d_in, const int* in_sizes, int n_in,
                              void* d_out, int out_size, void* d_ws,
                              size_t ws_size, hipStream_t stream) {
  const float* l = (const float*)d_in[0];
  const float* g = (const float*)d_in[1];
  const float* w = (const float*)d_in[2];
  float* out = (float*)d_out;
  float* ws = (float*)d_ws;  // [0,65536): G partials; [65536,65792): S
  fused_kernel<<<dim3(2 * N_ * F_), dim3(1024), 3 * TILE_F * sizeof(float),
                 stream>>>(l, g, w, out, ws);
  combine_kernel<<<dim3(32), dim3(1024), 0, stream>>>(out, ws);
}